// Round 1
// baseline (229.985 us; speedup 1.0000x reference)
//
#include <hip/hip_runtime.h>
#include <hip/hip_bf16.h>
#include <cstdint>
#include <cstddef>

typedef __attribute__((ext_vector_type(4))) float f32x4;
typedef __attribute__((ext_vector_type(8))) short bf16x8;

#define KDIM 768
#define BM 128
#define BN 128
#define BK 64

static __device__ __forceinline__ float sani(float x) {
  if (__builtin_isnan(x)) return 0.0f;
  if (__builtin_isinf(x)) return x > 0.0f ? 1.0e4f : -1.0e4f;
  return x;
}

// float -> bf16 bits, round-to-nearest-even
static __device__ __forceinline__ unsigned short f2bf(float x) {
  unsigned u = __builtin_bit_cast(unsigned, x);
  unsigned r = 0x7FFFu + ((u >> 16) & 1u);
  return (unsigned short)((u + r) >> 16);
}

__global__ __launch_bounds__(256) void prep_x_kernel(
    const float* __restrict__ h, unsigned short* __restrict__ xl,
    float* __restrict__ tx) {
  const int row = blockIdx.x;
  const int t = threadIdx.x;
  const float* src = h + (size_t)row * (KDIM + 1) + 1;  // skip given time comp
  float v0 = sani(src[t]);
  float v1 = sani(src[t + 256]);
  float v2 = sani(src[t + 512]);
  float ss = v0 * v0 + v1 * v1 + v2 * v2;
#pragma unroll
  for (int off = 32; off > 0; off >>= 1) ss += __shfl_down(ss, off);
  __shared__ float red[4];
  if ((t & 63) == 0) red[t >> 6] = ss;
  __syncthreads();
  if (t == 0) {
    float total = red[0] + red[1] + red[2] + red[3];
    tx[row] = sqrtf(1.0f + total);
  }
  unsigned short* dst = xl + (size_t)row * KDIM;
  dst[t]       = f2bf(v0);
  dst[t + 256] = f2bf(v1);
  dst[t + 512] = f2bf(v2);
}

__global__ __launch_bounds__(256) void prep_w_kernel(
    const float* __restrict__ w, unsigned short* __restrict__ wl,
    float* __restrict__ cw, int V) {
  const int row = blockIdx.x;
  const int t = threadIdx.x;
  unsigned short* dst = wl + (size_t)row * KDIM;
  if (row >= V) {  // zero-fill padded rows
    dst[t] = 0; dst[t + 256] = 0; dst[t + 512] = 0;
    if (t == 0) cw[row] = 0.0f;
    return;
  }
  const float* src = w + (size_t)row * KDIM;
  float v0 = src[t];
  float v1 = src[t + 256];
  float v2 = src[t + 512];
  float ss = v0 * v0 + v1 * v1 + v2 * v2;
#pragma unroll
  for (int off = 32; off > 0; off >>= 1) ss += __shfl_down(ss, off);
  __shared__ float red[4];
  if ((t & 63) == 0) red[t >> 6] = ss;
  __syncthreads();
  float total = red[0] + red[1] + red[2] + red[3];
  float r = sqrtf(total);
  float rc = fminf(r, 3.0f);
  float sc = sinhf(rc) / fmaxf(r, 1e-8f);
  dst[t]       = f2bf(sani(v0 * sc));
  dst[t + 256] = f2bf(sani(v1 * sc));
  dst[t + 512] = f2bf(sani(v2 * sc));
  if (t == 0) cw[row] = sani(coshf(rc));
}

#define GLD16(gp, sp)                                               \
  __builtin_amdgcn_global_load_lds(                                 \
      (const __attribute__((address_space(1))) void*)(gp),          \
      (__attribute__((address_space(3))) void*)(sp), 16, 0, 0)

__global__ __launch_bounds__(256) void gemm_kernel(
    const unsigned short* __restrict__ xl, const unsigned short* __restrict__ wl,
    const float* __restrict__ tx, const float* __restrict__ cw,
    const float* __restrict__ ls, float* __restrict__ out,
    int V, int Mtiles) {
  __shared__ unsigned short As[BM * BK];
  __shared__ unsigned short Bs[BN * BK];

  const int tid = threadIdx.x;
  const int lane = tid & 63;
  const int wid = tid >> 6;
  const int wr = wid >> 1;  // wave row (0..1)
  const int wc = wid & 1;   // wave col (0..1)
  const int bm = blockIdx.x % Mtiles;  // bn outer: consecutive blocks share B-tile (L2)
  const int bn = blockIdx.x / Mtiles;

  const int l15 = lane & 15;
  const int lq = lane >> 4;         // 0..3 (K quarter)
  const int srow = lane >> 3;       // staging: row within 8-row chunk
  const int scol = (lane & 7) * 8;  // staging: k offset (8 bf16 = 16B)

  f32x4 acc[4][4];
#pragma unroll
  for (int i = 0; i < 4; ++i)
#pragma unroll
    for (int j = 0; j < 4; ++j) acc[i][j] = (f32x4){0.f, 0.f, 0.f, 0.f};

  const size_t a_row0 = (size_t)bm * BM;
  const size_t b_row0 = (size_t)bn * BN;

  for (int kt = 0; kt < KDIM / BK; ++kt) {
    const int kbase = kt * BK;
    // stage A (128x64) and B (128x64) bf16 tiles: 16 wave-issues each of 1KB,
    // 4 per wave; LDS dest is wave-uniform base, global src per-lane.
#pragma unroll
    for (int c = 0; c < 4; ++c) {
      const int chunk = wid * 4 + c;
      const int row = chunk * 8 + srow;
      GLD16(xl + (a_row0 + row) * KDIM + kbase + scol, &As[chunk * 512]);
      GLD16(wl + (b_row0 + row) * KDIM + kbase + scol, &Bs[chunk * 512]);
    }
    asm volatile("s_waitcnt vmcnt(0)" ::: "memory");
    __syncthreads();
#pragma unroll
    for (int kk = 0; kk < 2; ++kk) {
      bf16x8 af[4], bfr[4];
#pragma unroll
      for (int mi = 0; mi < 4; ++mi)
        af[mi] = *(const bf16x8*)&As[(wr * 64 + mi * 16 + l15) * BK + kk * 32 + lq * 8];
#pragma unroll
      for (int ni = 0; ni < 4; ++ni)
        bfr[ni] = *(const bf16x8*)&Bs[(wc * 64 + ni * 16 + l15) * BK + kk * 32 + lq * 8];
#pragma unroll
      for (int mi = 0; mi < 4; ++mi)
#pragma unroll
        for (int ni = 0; ni < 4; ++ni)
          acc[mi][ni] = __builtin_amdgcn_mfma_f32_16x16x32_bf16(
              af[mi], bfr[ni], acc[mi][ni], 0, 0, 0);
    }
    __syncthreads();
  }

  float tau = ls[0];
  tau = fminf(fmaxf(tau, 0.01f), 2.5f);

  float cwv[4];
  int gn[4];
#pragma unroll
  for (int ni = 0; ni < 4; ++ni) {
    gn[ni] = bn * BN + wc * 64 + ni * 16 + l15;
    cwv[ni] = (gn[ni] < V) ? cw[gn[ni]] : 0.0f;
  }
#pragma unroll
  for (int mi = 0; mi < 4; ++mi) {
    const int rbase = bm * BM + wr * 64 + mi * 16 + lq * 4;
    const f32x4 t4 = *(const f32x4*)&tx[rbase];
#pragma unroll
    for (int ni = 0; ni < 4; ++ni) {
      if (gn[ni] < V) {
#pragma unroll
        for (int j = 0; j < 4; ++j) {
          out[(size_t)(rbase + j) * V + gn[ni]] =
              (acc[mi][ni][j] - t4[j] * cwv[ni]) * tau;
        }
      }
    }
  }
}

extern "C" void kernel_launch(void* const* d_in, const int* in_sizes, int n_in,
                              void* d_out, int out_size, void* d_ws, size_t ws_size,
                              hipStream_t stream) {
  const float* h = (const float*)d_in[0];
  const float* w = (const float*)d_in[1];
  const float* ls = (const float*)d_in[2];
  float* out = (float*)d_out;

  const int M = in_sizes[0] / (KDIM + 1);        // 1024
  const int V = in_sizes[1] / KDIM;              // 50257
  const int Vpad = (V + BN - 1) & ~(BN - 1);     // 50304

  // workspace layout: wl bf16 [Vpad*768] | xl bf16 [M*768] | cw f32 [Vpad] | tx f32 [M]
  char* ws = (char*)d_ws;
  unsigned short* wl = (unsigned short*)ws;
  unsigned short* xl = (unsigned short*)(ws + (size_t)Vpad * KDIM * 2);
  float* cw = (float*)(ws + (size_t)Vpad * KDIM * 2 + (size_t)M * KDIM * 2);
  float* tx = cw + Vpad;

  prep_x_kernel<<<dim3(M), dim3(256), 0, stream>>>(h, xl, tx);
  prep_w_kernel<<<dim3(Vpad), dim3(256), 0, stream>>>(w, wl, cw, V);

  const int Mtiles = M / BM;  // 8
  gemm_kernel<<<dim3(Mtiles * (Vpad / BN)), dim3(256), 0, stream>>>(
      xl, wl, tx, cw, ls, out, V, Mtiles);
}

// Round 2
// 190.028 us; speedup vs baseline: 1.2103x; 1.2103x over previous
//
#include <hip/hip_runtime.h>
#include <hip/hip_bf16.h>
#include <cstdint>
#include <cstddef>
#include <cstring>

typedef __attribute__((ext_vector_type(4))) float f32x4;
typedef __attribute__((ext_vector_type(8))) short bf16x8;

#define KDIM 768
#define BM 128
#define BN 128
#define BK 64

static __device__ __forceinline__ float sani(float x) {
  if (__builtin_isnan(x)) return 0.0f;
  if (__builtin_isinf(x)) return x > 0.0f ? 1.0e4f : -1.0e4f;
  return x;
}

// float -> bf16 bits, round-to-nearest-even
static __device__ __forceinline__ unsigned short f2bf(float x) {
  unsigned u = __builtin_bit_cast(unsigned, x);
  unsigned r = 0x7FFFu + ((u >> 16) & 1u);
  return (unsigned short)((u + r) >> 16);
}

// xl/wl are stored PRE-SWIZZLED: element e of row goes to e ^ ((row&7)<<3).
// XOR touches element bits 3-5 only => permutes 16B granules within each
// 64-elem (128B) K-tile; global_load_lds then stages linearly and the
// ds_read in the GEMM applies the same XOR (both-sides rule, m201/m231).

__global__ __launch_bounds__(256) void prep_x_kernel(
    const float* __restrict__ h, unsigned short* __restrict__ xl,
    float* __restrict__ tx) {
  const int row = blockIdx.x;
  const int t = threadIdx.x;
  const int swz = (row & 7) << 3;
  const float* src = h + (size_t)row * (KDIM + 1) + 1;  // skip given time comp
  float v0 = sani(src[t]);
  float v1 = sani(src[t + 256]);
  float v2 = sani(src[t + 512]);
  float ss = v0 * v0 + v1 * v1 + v2 * v2;
#pragma unroll
  for (int off = 32; off > 0; off >>= 1) ss += __shfl_down(ss, off);
  __shared__ float red[4];
  if ((t & 63) == 0) red[t >> 6] = ss;
  __syncthreads();
  if (t == 0) {
    float total = red[0] + red[1] + red[2] + red[3];
    tx[row] = sqrtf(1.0f + total);
  }
  unsigned short* dst = xl + (size_t)row * KDIM;
  dst[t ^ swz]         = f2bf(v0);
  dst[(t + 256) ^ swz] = f2bf(v1);
  dst[(t + 512) ^ swz] = f2bf(v2);
}

__global__ __launch_bounds__(256) void prep_w_kernel(
    const float* __restrict__ w, unsigned short* __restrict__ wl,
    float* __restrict__ cw, int V) {
  const int row = blockIdx.x;
  const int t = threadIdx.x;
  const int swz = (row & 7) << 3;
  unsigned short* dst = wl + (size_t)row * KDIM;
  if (row >= V) {  // zero-fill padded rows
    dst[t] = 0; dst[t + 256] = 0; dst[t + 512] = 0;
    if (t == 0) cw[row] = 0.0f;
    return;
  }
  const float* src = w + (size_t)row * KDIM;
  float v0 = src[t];
  float v1 = src[t + 256];
  float v2 = src[t + 512];
  float ss = v0 * v0 + v1 * v1 + v2 * v2;
#pragma unroll
  for (int off = 32; off > 0; off >>= 1) ss += __shfl_down(ss, off);
  __shared__ float red[4];
  if ((t & 63) == 0) red[t >> 6] = ss;
  __syncthreads();
  float total = red[0] + red[1] + red[2] + red[3];
  float r = sqrtf(total);
  float rc = fminf(r, 3.0f);
  float sc = sinhf(rc) / fmaxf(r, 1e-8f);
  dst[t ^ swz]         = f2bf(sani(v0 * sc));
  dst[(t + 256) ^ swz] = f2bf(sani(v1 * sc));
  dst[(t + 512) ^ swz] = f2bf(sani(v2 * sc));
  if (t == 0) cw[row] = sani(coshf(rc));
}

#define GLD16(gp, sp)                                               \
  __builtin_amdgcn_global_load_lds(                                 \
      (const __attribute__((address_space(1))) void*)(gp),          \
      (__attribute__((address_space(3))) void*)(sp), 16, 0, 0)

__global__ __launch_bounds__(256) void gemm_kernel(
    const unsigned short* __restrict__ xl, const unsigned short* __restrict__ wl,
    const float* __restrict__ tx, const float* __restrict__ cw,
    const float* __restrict__ ls, float* __restrict__ out,
    int V, int Mtiles, int nwg8) {
  __shared__ unsigned short As[BM * BK];
  __shared__ unsigned short Bs[BN * BK];

  const int tid = threadIdx.x;
  const int lane = tid & 63;
  const int wid = tid >> 6;
  const int wr = wid >> 1;  // wave row (0..1)
  const int wc = wid & 1;   // wave col (0..1)

  // chunked XCD swizzle: XCD x (= g%8) owns contiguous L-range => the 8
  // bm-blocks of one bn land on the SAME XCD's L2 (B-tile fetched once/XCD).
  const int g = blockIdx.x;
  const int L = (g & 7) * nwg8 + (g >> 3);
  const int bm = L & (Mtiles - 1);
  const int bn = L / Mtiles;

  const int l15 = lane & 15;
  const int lq = lane >> 4;         // 0..3 (K quarter)
  const int srow = lane >> 3;       // staging: row within 8-row chunk
  const int scol = (lane & 7) * 8;  // staging: k offset (8 bf16 = 16B)
  const int swz = (l15 & 7) << 3;   // ds_read element-XOR (matches storage)

  f32x4 acc[4][4];
#pragma unroll
  for (int i = 0; i < 4; ++i)
#pragma unroll
    for (int j = 0; j < 4; ++j) acc[i][j] = (f32x4){0.f, 0.f, 0.f, 0.f};

  const size_t a_row0 = (size_t)bm * BM;
  const size_t b_row0 = (size_t)bn * BN;

  for (int kt = 0; kt < KDIM / BK; ++kt) {
    const int kbase = kt * BK;
#pragma unroll
    for (int c = 0; c < 4; ++c) {
      const int chunk = wid * 4 + c;
      const int row = chunk * 8 + srow;
      GLD16(xl + (a_row0 + row) * KDIM + kbase + scol, &As[chunk * 512]);
      GLD16(wl + (b_row0 + row) * KDIM + kbase + scol, &Bs[chunk * 512]);
    }
    asm volatile("s_waitcnt vmcnt(0)" ::: "memory");
    __syncthreads();
#pragma unroll
    for (int kk = 0; kk < 2; ++kk) {
      const int koff = (kk * 32 + lq * 8) ^ swz;  // swizzled granule offset
      bf16x8 af[4], bfr[4];
#pragma unroll
      for (int mi = 0; mi < 4; ++mi)
        af[mi] = *(const bf16x8*)&As[(wr * 64 + mi * 16 + l15) * BK + koff];
#pragma unroll
      for (int ni = 0; ni < 4; ++ni)
        bfr[ni] = *(const bf16x8*)&Bs[(wc * 64 + ni * 16 + l15) * BK + koff];
      // swapped operands: D row-index (lq*4+j) = B rows (n), col (l15) = A rows (m)
#pragma unroll
      for (int mi = 0; mi < 4; ++mi)
#pragma unroll
        for (int ni = 0; ni < 4; ++ni)
          acc[mi][ni] = __builtin_amdgcn_mfma_f32_16x16x32_bf16(
              bfr[ni], af[mi], acc[mi][ni], 0, 0, 0);
    }
    __syncthreads();
  }

  float tau = ls[0];
  tau = fminf(fmaxf(tau, 0.01f), 2.5f);

#pragma unroll
  for (int mi = 0; mi < 4; ++mi) {
    const int mg = bm * BM + wr * 64 + mi * 16 + l15;
    const float txm = tx[mg];
    float* orow = out + (size_t)mg * V;
#pragma unroll
    for (int ni = 0; ni < 4; ++ni) {
      const int nb = bn * BN + wc * 64 + ni * 16 + lq * 4;
      const f32x4 cw4 = *(const f32x4*)&cw[nb];  // nb%4==0 -> 16B aligned
      f32x4 v;
#pragma unroll
      for (int j = 0; j < 4; ++j)
        v[j] = (acc[mi][ni][j] - txm * cw4[j]) * tau;
      if (nb + 3 < V) {
        __builtin_memcpy(&orow[nb], &v, 16);  // 4B-aligned 16B store
      } else {
#pragma unroll
        for (int j = 0; j < 4; ++j)
          if (nb + j < V) orow[nb + j] = v[j];
      }
    }
  }
}

extern "C" void kernel_launch(void* const* d_in, const int* in_sizes, int n_in,
                              void* d_out, int out_size, void* d_ws, size_t ws_size,
                              hipStream_t stream) {
  const float* h = (const float*)d_in[0];
  const float* w = (const float*)d_in[1];
  const float* ls = (const float*)d_in[2];
  float* out = (float*)d_out;

  const int M = in_sizes[0] / (KDIM + 1);        // 1024
  const int V = in_sizes[1] / KDIM;              // 50257
  const int Vpad = (V + BN - 1) & ~(BN - 1);     // 50304

  // workspace layout: wl bf16 [Vpad*768] | xl bf16 [M*768] | cw f32 [Vpad] | tx f32 [M]
  char* ws = (char*)d_ws;
  unsigned short* wl = (unsigned short*)ws;
  unsigned short* xl = (unsigned short*)(ws + (size_t)Vpad * KDIM * 2);
  float* cw = (float*)(ws + (size_t)Vpad * KDIM * 2 + (size_t)M * KDIM * 2);
  float* tx = cw + Vpad;

  prep_x_kernel<<<dim3(M), dim3(256), 0, stream>>>(h, xl, tx);
  prep_w_kernel<<<dim3(Vpad), dim3(256), 0, stream>>>(w, wl, cw, V);

  const int Mtiles = M / BM;                     // 8
  const int nwg = Mtiles * (Vpad / BN);          // 3144 (divisible by 8)
  gemm_kernel<<<dim3(nwg), dim3(256), 0, stream>>>(
      xl, wl, tx, cw, ls, out, V, Mtiles, nwg / 8);
}